// Round 2
// baseline (29151.501 us; speedup 1.0000x reference)
//
#include <hip/hip_runtime.h>

#define T_STEPS 512
#define NBATCH  64
#define HD      1024
#define ROWS    16    // batch rows per group
#define COLS    16    // h-columns per block
#define CPB     64    // column-blocks per group (4 groups * 64 = 256 blocks)

typedef unsigned short u16;
typedef unsigned int   u32;
typedef unsigned long long u64;
using short8  = __attribute__((ext_vector_type(8))) short;
using floatx4 = __attribute__((ext_vector_type(4))) float;

__device__ __forceinline__ u16 f2bf(float f) {
  u32 u = __float_as_uint(f);
  u32 r = (u + 0x7FFFu + ((u >> 16) & 1u)) >> 16;
  return (u16)r;
}
__device__ __forceinline__ float bf2f(u16 s) { return __uint_as_float(((u32)s) << 16); }
__device__ __forceinline__ float sigm(float x) { return 1.0f / (1.0f + __expf(-x)); }
__device__ __forceinline__ float tanh_(float x) { return 2.0f / (1.0f + __expf(-2.0f * x)) - 1.0f; }
// pack fp32 -> (bf16_hi<<16 | bf16_lo), ~2^-17 relative representation error
__device__ __forceinline__ u32 packhl(float f) {
  u16 h = f2bf(f);
  float r = f - bf2f(h);
  u16 l = f2bf(r);
  return ((u32)h << 16) | (u32)l;
}

// ---- ws layout (bytes) ----
#define OFF_H16   0ull                 // u32[64*1024] packed h (hi|lo)
#define OFF_S16   262144ull            // u32[64*1024] packed r.*h
#define OFF_BARX  524288ull            // barrier counters
#define OFF_WSPL  528384ull            // 6 weights x (hi,lo) bf16, each 1M u16
#define OFF_XHI   25694208ull          // bf16 hi of x, 33.5M u16
#define OFF_XLO   92803072ull
#define OFF_GATES 159911936ull         // [512][3][64][1024] fp32 (or fp16)
#define NEED32    562565120ull
#define NX        33554432ull          // x element count

// ---------------------------------------------------------------------------
// k_prep: split x and the 6 weight matrices into bf16 hi/lo arrays.
// w order: 0=wxr 1=wxz 2=wxh 3=whr 4=whz 5=whh
// ---------------------------------------------------------------------------
__global__ __launch_bounds__(256) void k_prep(
    const float* __restrict__ x,
    const float* __restrict__ wxr, const float* __restrict__ wxz, const float* __restrict__ wxh,
    const float* __restrict__ whr, const float* __restrict__ whz, const float* __restrict__ whh,
    u16* __restrict__ xhi, u16* __restrict__ xlo, u16* __restrict__ wspl)
{
  size_t i4 = ((size_t)blockIdx.x * 256 + threadIdx.x) * 4;
  const float* src; u16* dhi; u16* dlo; size_t off;
  if (i4 < NX) {
    src = x; dhi = xhi; dlo = xlo; off = i4;
  } else {
    size_t j = i4 - NX;
    int w = (int)(j >> 20);
    off = j & 1048575ull;
    if      (w == 0) src = wxr;
    else if (w == 1) src = wxz;
    else if (w == 2) src = wxh;
    else if (w == 3) src = whr;
    else if (w == 4) src = whz;
    else             src = whh;
    dhi = wspl + (size_t)w * 2097152ull;
    dlo = dhi + 1048576ull;
  }
  float4 v = *(const float4*)(src + off);
  u16 h0 = f2bf(v.x), h1 = f2bf(v.y), h2 = f2bf(v.z), h3 = f2bf(v.w);
  u16 l0 = f2bf(v.x - bf2f(h0)), l1 = f2bf(v.y - bf2f(h1));
  u16 l2 = f2bf(v.z - bf2f(h2)), l3 = f2bf(v.w - bf2f(h3));
  *(u64*)(dhi + off) = (u64)h0 | ((u64)h1 << 16) | ((u64)h2 << 32) | ((u64)h3 << 48);
  *(u64*)(dlo + off) = (u64)l0 | ((u64)l1 << 16) | ((u64)l2 << 32) | ((u64)l3 << 48);
}

// ---------------------------------------------------------------------------
// k_gates: G[t,gate,b,h] = x[t,b,:] @ Wx_gate[h,:] + b_gate[h], split-precision:
// acc += Ahi*Bhi + Ahi*Blo + Alo*Bhi  (3 chained MFMAs). 128x128 tile, BK=32.
// ---------------------------------------------------------------------------
__global__ __launch_bounds__(256) void k_gates(
    const u16* __restrict__ xhi, const u16* __restrict__ xlo,
    const u16* __restrict__ wspl,
    const float* __restrict__ bxr, const float* __restrict__ bxz, const float* __restrict__ bxh,
    void* __restrict__ gates, int g32)
{
  __shared__ __align__(16) u16 Ahi[128 * 32];
  __shared__ __align__(16) u16 Alo[128 * 32];
  __shared__ __align__(16) u16 Bhi[128 * 32];
  __shared__ __align__(16) u16 Blo[128 * 32];
  int bid = blockIdx.x;
  int nt = bid % 24, mt = bid / 24;
  int m0 = mt * 128, n0 = nt * 128;
  int gate = n0 >> 10;
  int nl0 = n0 & 1023;
  const u16* Whi = wspl + (size_t)gate * 2097152ull;
  const u16* Wlo = Whi + 1048576ull;
  const float* bias = (gate == 0) ? bxr : (gate == 1 ? bxz : bxh);
  int tid = threadIdx.x;
  int w = tid >> 6, lane = tid & 63;
  int l15 = lane & 15, l4 = lane >> 4;
  int wm = (w & 1) * 64, wn = (w >> 1) * 64;
  int srow = lane >> 2;
  int skol = (lane & 3) * 8;

  floatx4 acc[4][4];
#pragma unroll
  for (int i = 0; i < 4; ++i)
#pragma unroll
    for (int j = 0; j < 4; ++j) acc[i][j] = (floatx4){0.f, 0.f, 0.f, 0.f};

  for (int k0 = 0; k0 < 1024; k0 += 32) {
    __syncthreads();
#pragma unroll
    for (int cc = 0; cc < 2; ++cc) {
      int c = w + cc * 4;
      int rowA = m0 + c * 16 + srow;
      int rowB = nl0 + c * 16 + srow;
      __builtin_amdgcn_global_load_lds(
          (const __attribute__((address_space(1))) u32*)(xhi + (size_t)rowA * HD + k0 + skol),
          (__attribute__((address_space(3))) u32*)(Ahi + c * 512), 16, 0, 0);
      __builtin_amdgcn_global_load_lds(
          (const __attribute__((address_space(1))) u32*)(xlo + (size_t)rowA * HD + k0 + skol),
          (__attribute__((address_space(3))) u32*)(Alo + c * 512), 16, 0, 0);
      __builtin_amdgcn_global_load_lds(
          (const __attribute__((address_space(1))) u32*)(Whi + (size_t)rowB * HD + k0 + skol),
          (__attribute__((address_space(3))) u32*)(Bhi + c * 512), 16, 0, 0);
      __builtin_amdgcn_global_load_lds(
          (const __attribute__((address_space(1))) u32*)(Wlo + (size_t)rowB * HD + k0 + skol),
          (__attribute__((address_space(3))) u32*)(Blo + c * 512), 16, 0, 0);
    }
    __syncthreads();
    short8 ah[4], al[4], bh[4], bl[4];
#pragma unroll
    for (int i = 0; i < 4; ++i) {
      ah[i] = *(const short8*)&Ahi[(wm + i * 16 + l15) * 32 + l4 * 8];
      al[i] = *(const short8*)&Alo[(wm + i * 16 + l15) * 32 + l4 * 8];
    }
#pragma unroll
    for (int j = 0; j < 4; ++j) {
      bh[j] = *(const short8*)&Bhi[(wn + j * 16 + l15) * 32 + l4 * 8];
      bl[j] = *(const short8*)&Blo[(wn + j * 16 + l15) * 32 + l4 * 8];
    }
#pragma unroll
    for (int i = 0; i < 4; ++i)
#pragma unroll
      for (int j = 0; j < 4; ++j) {
        acc[i][j] = __builtin_amdgcn_mfma_f32_16x16x32_bf16(ah[i], bh[j], acc[i][j], 0, 0, 0);
        acc[i][j] = __builtin_amdgcn_mfma_f32_16x16x32_bf16(ah[i], bl[j], acc[i][j], 0, 0, 0);
        acc[i][j] = __builtin_amdgcn_mfma_f32_16x16x32_bf16(al[i], bh[j], acc[i][j], 0, 0, 0);
      }
  }

  float*     gf = (float*)gates;
  _Float16*  gh = (_Float16*)gates;
#pragma unroll
  for (int i = 0; i < 4; ++i) {
#pragma unroll
    for (int j = 0; j < 4; ++j) {
      int hcol = nl0 + wn + j * 16 + l15;
      float bv = bias[hcol];
#pragma unroll
      for (int r = 0; r < 4; ++r) {
        int m = m0 + wm + i * 16 + l4 * 4 + r;
        int t = m >> 6, bb = m & 63;
        size_t gidx = (((size_t)t * 3 + gate) * 64 + bb) * 1024 + hcol;
        float v = acc[i][j][r] + bv;
        if (g32) gf[gidx] = v; else gh[gidx] = (_Float16)v;
      }
    }
  }
}

// ---------------------------------------------------------------------------
// group barrier: monotonic epoch, agent-scope atomics, 64 blocks/group
// ---------------------------------------------------------------------------
__device__ __forceinline__ void grp_barrier(u32* cnt, u32* ep, unsigned target) {
  __syncthreads();                 // __syncthreads drains vmcnt -> our stores issued
  if (threadIdx.x == 0) {
    __threadfence();
    unsigned arrived =
        __hip_atomic_fetch_add(cnt, 1u, __ATOMIC_ACQ_REL, __HIP_MEMORY_SCOPE_AGENT) + 1;
    if (arrived == target * CPB) {
      __hip_atomic_store(ep, target, __ATOMIC_RELEASE, __HIP_MEMORY_SCOPE_AGENT);
    } else {
      while (__hip_atomic_load(ep, __ATOMIC_ACQUIRE, __HIP_MEMORY_SCOPE_AGENT) < target) {
        __builtin_amdgcn_s_sleep(2);
      }
    }
    __threadfence();
  }
  __syncthreads();
}

// ---------------------------------------------------------------------------
// k_scan: persistent, 256 blocks = 4 batch-groups x 64 column-blocks.
// h kept fp32 per-block; cross-block h/s as packed bf16 hi/lo u32 via relaxed
// agent-scope atomics. Split-precision recurrent MFMAs. 2 barriers/step.
// ---------------------------------------------------------------------------
__global__ __launch_bounds__(256) void k_scan(
    const float* __restrict__ state,
    const u16* __restrict__ wspl,
    const void* __restrict__ gates, int g32,
    u32* __restrict__ h16, u32* __restrict__ s16, u32* __restrict__ barx,
    float* __restrict__ yout)
{
  __shared__ __align__(16) u16 hAhi[ROWS * 1032];
  __shared__ __align__(16) u16 hAlo[ROWS * 1032];
  __shared__ floatx4 redv[8 * 64];
  __shared__ float uS[ROWS * COLS];
  __shared__ float pS[ROWS * COLS];
  __shared__ float hP[ROWS * COLS];

  int bid = blockIdx.x;
  int grp = bid >> 6;
  int cb  = bid & 63;
  int R0 = grp * ROWS;
  int J0 = cb * COLS;
  int tid = threadIdx.x;
  int w = tid >> 6, lane = tid & 63;
  int l15 = lane & 15, l4 = lane >> 4;
  int wbase = w * 256;

  u32* cntp = barx + grp * 32;
  u32* epp  = barx + grp * 32 + 16;
  const float*    gf = (const float*)gates;
  const _Float16* gh = (const _Float16*)gates;

  const u16* wrHi = wspl + 3ull * 2097152ull + (size_t)(J0 + l15) * HD;
  const u16* wrLo = wrHi + 1048576ull;
  const u16* wzHi = wspl + 4ull * 2097152ull + (size_t)(J0 + l15) * HD;
  const u16* wzLo = wzHi + 1048576ull;
  const u16* whHi = wspl + 5ull * 2097152ull + (size_t)(J0 + l15) * HD;
  const u16* whLo = whHi + 1048576ull;

  { // init h patch + publish
    int row = tid >> 4, col = tid & 15;
    float h0 = state[(size_t)(R0 + row) * HD + J0 + col];
    hP[row * 16 + col] = h0;
    __hip_atomic_store(h16 + (size_t)(R0 + row) * HD + J0 + col, packhl(h0),
                       __ATOMIC_RELAXED, __HIP_MEMORY_SCOPE_AGENT);
  }
  unsigned tgt = 1;
  grp_barrier(cntp, epp, tgt); ++tgt;

  for (int t = 0; t < T_STEPS; ++t) {
    // ---------- phase A: r,z ----------
#pragma unroll 4
    for (int rr = 0; rr < ROWS * 2; ++rr) {
      int row = rr >> 1, half = rr & 1;
      int c0 = half * 512 + tid * 2;
      u64 v = __hip_atomic_load((const u64*)(h16 + (size_t)(R0 + row) * HD + c0),
                                __ATOMIC_RELAXED, __HIP_MEMORY_SCOPE_AGENT);
      u32 e0 = (u32)v, e1 = (u32)(v >> 32);
      *(u32*)&hAhi[row * 1032 + c0] = (e0 >> 16) | (e1 & 0xFFFF0000u);
      *(u32*)&hAlo[row * 1032 + c0] = (e0 & 0xFFFFu) | (e1 << 16);
    }
    __syncthreads();
    floatx4 accR = {0.f, 0.f, 0.f, 0.f}, accZ = {0.f, 0.f, 0.f, 0.f};
#pragma unroll
    for (int kk = 0; kk < 8; ++kk) {
      int k = wbase + kk * 32 + l4 * 8;
      short8 ahi = *(const short8*)&hAhi[l15 * 1032 + k];
      short8 alo = *(const short8*)&hAlo[l15 * 1032 + k];
      short8 brh = *(const short8*)(wrHi + k);
      short8 brl = *(const short8*)(wrLo + k);
      short8 bzh = *(const short8*)(wzHi + k);
      short8 bzl = *(const short8*)(wzLo + k);
      accR = __builtin_amdgcn_mfma_f32_16x16x32_bf16(ahi, brh, accR, 0, 0, 0);
      accR = __builtin_amdgcn_mfma_f32_16x16x32_bf16(ahi, brl, accR, 0, 0, 0);
      accR = __builtin_amdgcn_mfma_f32_16x16x32_bf16(alo, brh, accR, 0, 0, 0);
      accZ = __builtin_amdgcn_mfma_f32_16x16x32_bf16(ahi, bzh, accZ, 0, 0, 0);
      accZ = __builtin_amdgcn_mfma_f32_16x16x32_bf16(ahi, bzl, accZ, 0, 0, 0);
      accZ = __builtin_amdgcn_mfma_f32_16x16x32_bf16(alo, bzh, accZ, 0, 0, 0);
    }
    redv[(w * 2 + 0) * 64 + lane] = accR;
    redv[(w * 2 + 1) * 64 + lane] = accZ;
    __syncthreads();
    if (w < 2) {
      floatx4 sum = redv[(0 + w) * 64 + lane];
      sum += redv[(2 + w) * 64 + lane];
      sum += redv[(4 + w) * 64 + lane];
      sum += redv[(6 + w) * 64 + lane];
#pragma unroll
      for (int r = 0; r < 4; ++r) {
        int row = l4 * 4 + r;
        int gb = R0 + row;
        size_t gidx = (((size_t)t * 3 + w) * 64 + gb) * 1024 + (J0 + l15);
        float g = g32 ? gf[gidx] : (float)gh[gidx];
        float sg = sigm(sum[r] + g);
        if (w == 0) pS[row * 16 + l15] = sg * hP[row * 16 + l15];
        else        uS[row * 16 + l15] = sg;
      }
    }
    __syncthreads();
    { // publish s = r.*h
      int row = tid >> 4, col = tid & 15;
      __hip_atomic_store(s16 + (size_t)(R0 + row) * HD + J0 + col, packhl(pS[row * 16 + col]),
                         __ATOMIC_RELAXED, __HIP_MEMORY_SCOPE_AGENT);
    }
    grp_barrier(cntp, epp, tgt); ++tgt;

    // ---------- phase B: candidate + update ----------
#pragma unroll 4
    for (int rr = 0; rr < ROWS * 2; ++rr) {
      int row = rr >> 1, half = rr & 1;
      int c0 = half * 512 + tid * 2;
      u64 v = __hip_atomic_load((const u64*)(s16 + (size_t)(R0 + row) * HD + c0),
                                __ATOMIC_RELAXED, __HIP_MEMORY_SCOPE_AGENT);
      u32 e0 = (u32)v, e1 = (u32)(v >> 32);
      *(u32*)&hAhi[row * 1032 + c0] = (e0 >> 16) | (e1 & 0xFFFF0000u);
      *(u32*)&hAlo[row * 1032 + c0] = (e0 & 0xFFFFu) | (e1 << 16);
    }
    __syncthreads();
    floatx4 accH = {0.f, 0.f, 0.f, 0.f};
#pragma unroll
    for (int kk = 0; kk < 8; ++kk) {
      int k = wbase + kk * 32 + l4 * 8;
      short8 ahi = *(const short8*)&hAhi[l15 * 1032 + k];
      short8 alo = *(const short8*)&hAlo[l15 * 1032 + k];
      short8 bhh = *(const short8*)(whHi + k);
      short8 bhl = *(const short8*)(whLo + k);
      accH = __builtin_amdgcn_mfma_f32_16x16x32_bf16(ahi, bhh, accH, 0, 0, 0);
      accH = __builtin_amdgcn_mfma_f32_16x16x32_bf16(ahi, bhl, accH, 0, 0, 0);
      accH = __builtin_amdgcn_mfma_f32_16x16x32_bf16(alo, bhh, accH, 0, 0, 0);
    }
    redv[w * 64 + lane] = accH;
    __syncthreads();
    if (w == 0) {
      floatx4 sum = redv[lane];
      sum += redv[64 + lane];
      sum += redv[128 + lane];
      sum += redv[192 + lane];
#pragma unroll
      for (int r = 0; r < 4; ++r) {
        int row = l4 * 4 + r;
        int gb = R0 + row;
        size_t gidx = (((size_t)t * 3 + 2) * 64 + gb) * 1024 + (J0 + l15);
        float g = g32 ? gf[gidx] : (float)gh[gidx];
        float hc = tanh_(sum[r] + g);
        float u = uS[row * 16 + l15];
        float ho = hP[row * 16 + l15];
        float hn = u * ho + (1.0f - u) * hc;
        hP[row * 16 + l15] = hn;
        pS[row * 16 + l15] = hn;
        yout[((size_t)t * NBATCH + gb) * HD + J0 + l15] = hn;
      }
    }
    __syncthreads();
    { // publish h_new
      int row = tid >> 4, col = tid & 15;
      __hip_atomic_store(h16 + (size_t)(R0 + row) * HD + J0 + col, packhl(pS[row * 16 + col]),
                         __ATOMIC_RELAXED, __HIP_MEMORY_SCOPE_AGENT);
    }
    grp_barrier(cntp, epp, tgt); ++tgt;
  }

  __syncthreads();
  { // final state
    int row = tid >> 4, col = tid & 15;
    float* fout = yout + (size_t)T_STEPS * NBATCH * HD;
    fout[(size_t)(R0 + row) * HD + J0 + col] = hP[row * 16 + col];
  }
}

// ---------------------------------------------------------------------------
extern "C" void kernel_launch(void* const* d_in, const int* in_sizes, int n_in,
                              void* d_out, int out_size, void* d_ws, size_t ws_size,
                              hipStream_t stream) {
  const float* x   = (const float*)d_in[0];
  const float* st  = (const float*)d_in[1];
  const float* wxr = (const float*)d_in[2];
  const float* bxr = (const float*)d_in[3];
  const float* whr = (const float*)d_in[4];
  const float* wxz = (const float*)d_in[5];
  const float* bxz = (const float*)d_in[6];
  const float* whz = (const float*)d_in[7];
  const float* wxh = (const float*)d_in[8];
  const float* bxh = (const float*)d_in[9];
  const float* whh = (const float*)d_in[10];
  float* yout = (float*)d_out;

  char* ws = (char*)d_ws;
  u32* h16  = (u32*)(ws + OFF_H16);
  u32* s16  = (u32*)(ws + OFF_S16);
  u32* barx = (u32*)(ws + OFF_BARX);
  u16* wspl = (u16*)(ws + OFF_WSPL);
  u16* xhi  = (u16*)(ws + OFF_XHI);
  u16* xlo  = (u16*)(ws + OFF_XLO);
  void* gates = (void*)(ws + OFF_GATES);
  int g32 = (ws_size >= NEED32) ? 1 : 0;

  hipMemsetAsync(barx, 0, 4096, stream);
  // 39,845,888 elements / 4 per thread / 256 threads = 38912 blocks
  k_prep<<<dim3(38912), dim3(256), 0, stream>>>(x, wxr, wxz, wxh, whr, whz, whh,
                                                xhi, xlo, wspl);
  k_gates<<<dim3(6144), dim3(256), 0, stream>>>(xhi, xlo, wspl, bxr, bxz, bxh, gates, g32);
  k_scan<<<dim3(256), dim3(256), 0, stream>>>(st, wspl, gates, g32, h16, s16, barx, yout);
}

// Round 3
// 13303.865 us; speedup vs baseline: 2.1912x; 2.1912x over previous
//
#include <hip/hip_runtime.h>

#define T_STEPS 512
#define NBATCH  64
#define HD      1024
#define ROWS    16    // batch rows per group
#define COLS    16    // h-columns per block
#define CPB     64    // column-blocks per group (4 groups * 64 = 256 blocks)
#define PADW    1064  // LDS row stride in u16: 532 dwords == 20 mod 32 (conflict-breaking)

typedef unsigned short u16;
typedef unsigned int   u32;
typedef unsigned long long u64;
using short8  = __attribute__((ext_vector_type(8))) short;
using floatx4 = __attribute__((ext_vector_type(4))) float;

__device__ __forceinline__ u16 f2bf(float f) {
  u32 u = __float_as_uint(f);
  u32 r = (u + 0x7FFFu + ((u >> 16) & 1u)) >> 16;
  return (u16)r;
}
__device__ __forceinline__ float bf2f(u16 s) { return __uint_as_float(((u32)s) << 16); }
__device__ __forceinline__ float sigm(float x) { return 1.0f / (1.0f + __expf(-x)); }
__device__ __forceinline__ float tanh_(float x) { return 2.0f / (1.0f + __expf(-2.0f * x)) - 1.0f; }
// pack fp32 -> (bf16_hi<<16 | bf16_lo), ~2^-17 relative representation error
__device__ __forceinline__ u32 packhl(float f) {
  u16 h = f2bf(f);
  float r = f - bf2f(h);
  u16 l = f2bf(r);
  return ((u32)h << 16) | (u32)l;
}

// ---- ws layout (bytes) ----
#define OFF_H16   0ull                 // u32[64*1024] packed h (hi|lo)
#define OFF_S16   262144ull            // u32[64*1024] packed r.*h
#define OFF_BARX  524288ull            // barrier counters (4 groups x 1KB)
#define OFF_WSPL  528384ull            // 6 weights x (hi,lo) bf16, each 1M u16
#define OFF_XHI   25694208ull          // bf16 hi of x, 33.5M u16
#define OFF_XLO   92803072ull
#define OFF_GATES 159911936ull         // [512][3][64][1024] fp32 (or fp16)
#define NEED32    562565120ull
#define NX        33554432ull          // x element count

// ---------------------------------------------------------------------------
// k_prep: split x and the 6 weight matrices into bf16 hi/lo arrays.
// w order: 0=wxr 1=wxz 2=wxh 3=whr 4=whz 5=whh
// ---------------------------------------------------------------------------
__global__ __launch_bounds__(256) void k_prep(
    const float* __restrict__ x,
    const float* __restrict__ wxr, const float* __restrict__ wxz, const float* __restrict__ wxh,
    const float* __restrict__ whr, const float* __restrict__ whz, const float* __restrict__ whh,
    u16* __restrict__ xhi, u16* __restrict__ xlo, u16* __restrict__ wspl)
{
  size_t i4 = ((size_t)blockIdx.x * 256 + threadIdx.x) * 4;
  const float* src; u16* dhi; u16* dlo; size_t off;
  if (i4 < NX) {
    src = x; dhi = xhi; dlo = xlo; off = i4;
  } else {
    size_t j = i4 - NX;
    int w = (int)(j >> 20);
    off = j & 1048575ull;
    if      (w == 0) src = wxr;
    else if (w == 1) src = wxz;
    else if (w == 2) src = wxh;
    else if (w == 3) src = whr;
    else if (w == 4) src = whz;
    else             src = whh;
    dhi = wspl + (size_t)w * 2097152ull;
    dlo = dhi + 1048576ull;
  }
  float4 v = *(const float4*)(src + off);
  u16 h0 = f2bf(v.x), h1 = f2bf(v.y), h2 = f2bf(v.z), h3 = f2bf(v.w);
  u16 l0 = f2bf(v.x - bf2f(h0)), l1 = f2bf(v.y - bf2f(h1));
  u16 l2 = f2bf(v.z - bf2f(h2)), l3 = f2bf(v.w - bf2f(h3));
  *(u64*)(dhi + off) = (u64)h0 | ((u64)h1 << 16) | ((u64)h2 << 32) | ((u64)h3 << 48);
  *(u64*)(dlo + off) = (u64)l0 | ((u64)l1 << 16) | ((u64)l2 << 32) | ((u64)l3 << 48);
}

// ---------------------------------------------------------------------------
// k_gates: G[t,gate,b,h] = x[t,b,:] @ Wx_gate[h,:] + b_gate[h], split-precision:
// acc += Ahi*Bhi + Ahi*Blo + Alo*Bhi  (3 chained MFMAs). 128x128 tile, BK=32.
// ---------------------------------------------------------------------------
__global__ __launch_bounds__(256) void k_gates(
    const u16* __restrict__ xhi, const u16* __restrict__ xlo,
    const u16* __restrict__ wspl,
    const float* __restrict__ bxr, const float* __restrict__ bxz, const float* __restrict__ bxh,
    void* __restrict__ gates, int g32)
{
  __shared__ __align__(16) u16 Ahi[128 * 32];
  __shared__ __align__(16) u16 Alo[128 * 32];
  __shared__ __align__(16) u16 Bhi[128 * 32];
  __shared__ __align__(16) u16 Blo[128 * 32];
  int bid = blockIdx.x;
  int nt = bid % 24, mt = bid / 24;
  int m0 = mt * 128, n0 = nt * 128;
  int gate = n0 >> 10;
  int nl0 = n0 & 1023;
  const u16* Whi = wspl + (size_t)gate * 2097152ull;
  const u16* Wlo = Whi + 1048576ull;
  const float* bias = (gate == 0) ? bxr : (gate == 1 ? bxz : bxh);
  int tid = threadIdx.x;
  int w = tid >> 6, lane = tid & 63;
  int l15 = lane & 15, l4 = lane >> 4;
  int wm = (w & 1) * 64, wn = (w >> 1) * 64;
  int srow = lane >> 2;
  int skol = (lane & 3) * 8;

  floatx4 acc[4][4];
#pragma unroll
  for (int i = 0; i < 4; ++i)
#pragma unroll
    for (int j = 0; j < 4; ++j) acc[i][j] = (floatx4){0.f, 0.f, 0.f, 0.f};

  for (int k0 = 0; k0 < 1024; k0 += 32) {
    __syncthreads();
#pragma unroll
    for (int cc = 0; cc < 2; ++cc) {
      int c = w + cc * 4;
      int rowA = m0 + c * 16 + srow;
      int rowB = nl0 + c * 16 + srow;
      __builtin_amdgcn_global_load_lds(
          (const __attribute__((address_space(1))) u32*)(xhi + (size_t)rowA * HD + k0 + skol),
          (__attribute__((address_space(3))) u32*)(Ahi + c * 512), 16, 0, 0);
      __builtin_amdgcn_global_load_lds(
          (const __attribute__((address_space(1))) u32*)(xlo + (size_t)rowA * HD + k0 + skol),
          (__attribute__((address_space(3))) u32*)(Alo + c * 512), 16, 0, 0);
      __builtin_amdgcn_global_load_lds(
          (const __attribute__((address_space(1))) u32*)(Whi + (size_t)rowB * HD + k0 + skol),
          (__attribute__((address_space(3))) u32*)(Bhi + c * 512), 16, 0, 0);
      __builtin_amdgcn_global_load_lds(
          (const __attribute__((address_space(1))) u32*)(Wlo + (size_t)rowB * HD + k0 + skol),
          (__attribute__((address_space(3))) u32*)(Blo + c * 512), 16, 0, 0);
    }
    __syncthreads();
    short8 ah[4], al[4], bh[4], bl[4];
#pragma unroll
    for (int i = 0; i < 4; ++i) {
      ah[i] = *(const short8*)&Ahi[(wm + i * 16 + l15) * 32 + l4 * 8];
      al[i] = *(const short8*)&Alo[(wm + i * 16 + l15) * 32 + l4 * 8];
    }
#pragma unroll
    for (int j = 0; j < 4; ++j) {
      bh[j] = *(const short8*)&Bhi[(wn + j * 16 + l15) * 32 + l4 * 8];
      bl[j] = *(const short8*)&Blo[(wn + j * 16 + l15) * 32 + l4 * 8];
    }
#pragma unroll
    for (int i = 0; i < 4; ++i)
#pragma unroll
      for (int j = 0; j < 4; ++j) {
        acc[i][j] = __builtin_amdgcn_mfma_f32_16x16x32_bf16(ah[i], bh[j], acc[i][j], 0, 0, 0);
        acc[i][j] = __builtin_amdgcn_mfma_f32_16x16x32_bf16(ah[i], bl[j], acc[i][j], 0, 0, 0);
        acc[i][j] = __builtin_amdgcn_mfma_f32_16x16x32_bf16(al[i], bh[j], acc[i][j], 0, 0, 0);
      }
  }

  float*     gf = (float*)gates;
  _Float16*  gh = (_Float16*)gates;
#pragma unroll
  for (int i = 0; i < 4; ++i) {
#pragma unroll
    for (int j = 0; j < 4; ++j) {
      int hcol = nl0 + wn + j * 16 + l15;
      float bv = bias[hcol];
#pragma unroll
      for (int r = 0; r < 4; ++r) {
        int m = m0 + wm + i * 16 + l4 * 4 + r;
        int t = m >> 6, bb = m & 63;
        size_t gidx = (((size_t)t * 3 + gate) * 64 + bb) * 1024 + hcol;
        float v = acc[i][j][r] + bv;
        if (g32) gf[gidx] = v; else gh[gidx] = (_Float16)v;
      }
    }
  }
}

// ---------------------------------------------------------------------------
// group barrier: FENCE-FREE. All cross-block data moves via sc1 agent-scope
// relaxed atomics (bypass non-coherent L1/L2), and __syncthreads drains each
// wave's vmcnt (stores visible at MALL) before the counter bump. No
// buffer_wbl2 / buffer_inv -> L2-resident weights stay cached.
// cnt and ep on separate 256B lines to avoid RMW/spin contention.
// ---------------------------------------------------------------------------
__device__ __forceinline__ void grp_barrier(u32* cnt, u32* ep, unsigned target) {
  __syncthreads();
  if (threadIdx.x == 0) {
    unsigned arrived =
        __hip_atomic_fetch_add(cnt, 1u, __ATOMIC_RELAXED, __HIP_MEMORY_SCOPE_AGENT) + 1;
    if (arrived == target * CPB) {
      __hip_atomic_store(ep, target, __ATOMIC_RELAXED, __HIP_MEMORY_SCOPE_AGENT);
    } else {
      while (__hip_atomic_load(ep, __ATOMIC_RELAXED, __HIP_MEMORY_SCOPE_AGENT) < target) {
        __builtin_amdgcn_s_sleep(1);
      }
    }
  }
  __syncthreads();
}

// ---------------------------------------------------------------------------
// k_scan: persistent, 256 blocks = 4 batch-groups x 64 column-blocks.
// h kept fp32 per-block; cross-block h/s as packed bf16 hi/lo u32 via relaxed
// agent-scope atomics. Split-precision recurrent MFMAs. 2 barriers/step.
// Gate values for the step are register-prefetched at loop top (overlap HBM
// latency with staging+MFMA).
// ---------------------------------------------------------------------------
__global__ __launch_bounds__(256) void k_scan(
    const float* __restrict__ state,
    const u16* __restrict__ wspl,
    const void* __restrict__ gates, int g32,
    u32* __restrict__ h16, u32* __restrict__ s16, u32* __restrict__ barx,
    float* __restrict__ yout)
{
  __shared__ __align__(16) u16 hAhi[ROWS * PADW];
  __shared__ __align__(16) u16 hAlo[ROWS * PADW];
  __shared__ floatx4 redv[8 * 64];
  __shared__ float uS[ROWS * COLS];
  __shared__ float pS[ROWS * COLS];
  __shared__ float hP[ROWS * COLS];

  int bid = blockIdx.x;
  int grp = bid >> 6;
  int cb  = bid & 63;
  int R0 = grp * ROWS;
  int J0 = cb * COLS;
  int tid = threadIdx.x;
  int w = tid >> 6, lane = tid & 63;
  int l15 = lane & 15, l4 = lane >> 4;
  int wbase = w * 256;

  u32* cntp = barx + grp * 256;
  u32* epp  = barx + grp * 256 + 64;
  const float*    gf = (const float*)gates;
  const _Float16* gh = (const _Float16*)gates;

  const u16* wrHi = wspl + 3ull * 2097152ull + (size_t)(J0 + l15) * HD;
  const u16* wrLo = wrHi + 1048576ull;
  const u16* wzHi = wspl + 4ull * 2097152ull + (size_t)(J0 + l15) * HD;
  const u16* wzLo = wzHi + 1048576ull;
  const u16* whHi = wspl + 5ull * 2097152ull + (size_t)(J0 + l15) * HD;
  const u16* whLo = whHi + 1048576ull;

  { // init h patch + publish
    int row = tid >> 4, col = tid & 15;
    float h0 = state[(size_t)(R0 + row) * HD + J0 + col];
    hP[row * 16 + col] = h0;
    __hip_atomic_store(h16 + (size_t)(R0 + row) * HD + J0 + col, packhl(h0),
                       __ATOMIC_RELAXED, __HIP_MEMORY_SCOPE_AGENT);
  }
  unsigned tgt = 1;
  grp_barrier(cntp, epp, tgt); ++tgt;

  for (int t = 0; t < T_STEPS; ++t) {
    // ---- register-prefetch this step's gate values (independent of barrier)
    float gA[4] = {0.f, 0.f, 0.f, 0.f};
    float gB[4] = {0.f, 0.f, 0.f, 0.f};
    if (w < 2) {
#pragma unroll
      for (int r = 0; r < 4; ++r) {
        size_t gidx = (((size_t)t * 3 + w) * 64 + (R0 + l4 * 4 + r)) * 1024 + (J0 + l15);
        gA[r] = g32 ? gf[gidx] : (float)gh[gidx];
      }
    }
    if (w == 0) {
#pragma unroll
      for (int r = 0; r < 4; ++r) {
        size_t gidx = (((size_t)t * 3 + 2) * 64 + (R0 + l4 * 4 + r)) * 1024 + (J0 + l15);
        gB[r] = g32 ? gf[gidx] : (float)gh[gidx];
      }
    }

    // ---------- phase A: r,z ----------
#pragma unroll 4
    for (int rr = 0; rr < ROWS * 2; ++rr) {
      int row = rr >> 1, half = rr & 1;
      int c0 = half * 512 + tid * 2;
      u64 v = __hip_atomic_load((const u64*)(h16 + (size_t)(R0 + row) * HD + c0),
                                __ATOMIC_RELAXED, __HIP_MEMORY_SCOPE_AGENT);
      u32 e0 = (u32)v, e1 = (u32)(v >> 32);
      *(u32*)&hAhi[row * PADW + c0] = (e0 >> 16) | (e1 & 0xFFFF0000u);
      *(u32*)&hAlo[row * PADW + c0] = (e0 & 0xFFFFu) | (e1 << 16);
    }
    __syncthreads();
    floatx4 accR = {0.f, 0.f, 0.f, 0.f}, accZ = {0.f, 0.f, 0.f, 0.f};
#pragma unroll
    for (int kk = 0; kk < 8; ++kk) {
      int k = wbase + kk * 32 + l4 * 8;
      short8 ahi = *(const short8*)&hAhi[l15 * PADW + k];
      short8 alo = *(const short8*)&hAlo[l15 * PADW + k];
      short8 brh = *(const short8*)(wrHi + k);
      short8 brl = *(const short8*)(wrLo + k);
      short8 bzh = *(const short8*)(wzHi + k);
      short8 bzl = *(const short8*)(wzLo + k);
      accR = __builtin_amdgcn_mfma_f32_16x16x32_bf16(ahi, brh, accR, 0, 0, 0);
      accR = __builtin_amdgcn_mfma_f32_16x16x32_bf16(ahi, brl, accR, 0, 0, 0);
      accR = __builtin_amdgcn_mfma_f32_16x16x32_bf16(alo, brh, accR, 0, 0, 0);
      accZ = __builtin_amdgcn_mfma_f32_16x16x32_bf16(ahi, bzh, accZ, 0, 0, 0);
      accZ = __builtin_amdgcn_mfma_f32_16x16x32_bf16(ahi, bzl, accZ, 0, 0, 0);
      accZ = __builtin_amdgcn_mfma_f32_16x16x32_bf16(alo, bzh, accZ, 0, 0, 0);
    }
    redv[(w * 2 + 0) * 64 + lane] = accR;
    redv[(w * 2 + 1) * 64 + lane] = accZ;
    __syncthreads();
    if (w < 2) {
      floatx4 sum = redv[(0 + w) * 64 + lane];
      sum += redv[(2 + w) * 64 + lane];
      sum += redv[(4 + w) * 64 + lane];
      sum += redv[(6 + w) * 64 + lane];
#pragma unroll
      for (int r = 0; r < 4; ++r) {
        int row = l4 * 4 + r;
        float sg = sigm(sum[r] + gA[r]);
        if (w == 0) pS[row * 16 + l15] = sg * hP[row * 16 + l15];
        else        uS[row * 16 + l15] = sg;
      }
    }
    __syncthreads();
    { // publish s = r.*h
      int row = tid >> 4, col = tid & 15;
      __hip_atomic_store(s16 + (size_t)(R0 + row) * HD + J0 + col, packhl(pS[row * 16 + col]),
                         __ATOMIC_RELAXED, __HIP_MEMORY_SCOPE_AGENT);
    }
    grp_barrier(cntp, epp, tgt); ++tgt;

    // ---------- phase B: candidate + update ----------
#pragma unroll 4
    for (int rr = 0; rr < ROWS * 2; ++rr) {
      int row = rr >> 1, half = rr & 1;
      int c0 = half * 512 + tid * 2;
      u64 v = __hip_atomic_load((const u64*)(s16 + (size_t)(R0 + row) * HD + c0),
                                __ATOMIC_RELAXED, __HIP_MEMORY_SCOPE_AGENT);
      u32 e0 = (u32)v, e1 = (u32)(v >> 32);
      *(u32*)&hAhi[row * PADW + c0] = (e0 >> 16) | (e1 & 0xFFFF0000u);
      *(u32*)&hAlo[row * PADW + c0] = (e0 & 0xFFFFu) | (e1 << 16);
    }
    __syncthreads();
    floatx4 accH = {0.f, 0.f, 0.f, 0.f};
#pragma unroll
    for (int kk = 0; kk < 8; ++kk) {
      int k = wbase + kk * 32 + l4 * 8;
      short8 ahi = *(const short8*)&hAhi[l15 * PADW + k];
      short8 alo = *(const short8*)&hAlo[l15 * PADW + k];
      short8 bhh = *(const short8*)(whHi + k);
      short8 bhl = *(const short8*)(whLo + k);
      accH = __builtin_amdgcn_mfma_f32_16x16x32_bf16(ahi, bhh, accH, 0, 0, 0);
      accH = __builtin_amdgcn_mfma_f32_16x16x32_bf16(ahi, bhl, accH, 0, 0, 0);
      accH = __builtin_amdgcn_mfma_f32_16x16x32_bf16(alo, bhh, accH, 0, 0, 0);
    }
    redv[w * 64 + lane] = accH;
    __syncthreads();
    if (w == 0) {
      floatx4 sum = redv[lane];
      sum += redv[64 + lane];
      sum += redv[128 + lane];
      sum += redv[192 + lane];
#pragma unroll
      for (int r = 0; r < 4; ++r) {
        int row = l4 * 4 + r;
        int gb = R0 + row;
        float hc = tanh_(sum[r] + gB[r]);
        float u = uS[row * 16 + l15];
        float ho = hP[row * 16 + l15];
        float hn = u * ho + (1.0f - u) * hc;
        hP[row * 16 + l15] = hn;
        pS[row * 16 + l15] = hn;
        yout[((size_t)t * NBATCH + gb) * HD + J0 + l15] = hn;
      }
    }
    __syncthreads();
    { // publish h_new
      int row = tid >> 4, col = tid & 15;
      __hip_atomic_store(h16 + (size_t)(R0 + row) * HD + J0 + col, packhl(pS[row * 16 + col]),
                         __ATOMIC_RELAXED, __HIP_MEMORY_SCOPE_AGENT);
    }
    grp_barrier(cntp, epp, tgt); ++tgt;
  }

  __syncthreads();
  { // final state
    int row = tid >> 4, col = tid & 15;
    float* fout = yout + (size_t)T_STEPS * NBATCH * HD;
    fout[(size_t)(R0 + row) * HD + J0 + col] = hP[row * 16 + col];
  }
}

// ---------------------------------------------------------------------------
extern "C" void kernel_launch(void* const* d_in, const int* in_sizes, int n_in,
                              void* d_out, int out_size, void* d_ws, size_t ws_size,
                              hipStream_t stream) {
  const float* x   = (const float*)d_in[0];
  const float* st  = (const float*)d_in[1];
  const float* wxr = (const float*)d_in[2];
  const float* bxr = (const float*)d_in[3];
  const float* whr = (const float*)d_in[4];
  const float* wxz = (const float*)d_in[5];
  const float* bxz = (const float*)d_in[6];
  const float* whz = (const float*)d_in[7];
  const float* wxh = (const float*)d_in[8];
  const float* bxh = (const float*)d_in[9];
  const float* whh = (const float*)d_in[10];
  float* yout = (float*)d_out;

  char* ws = (char*)d_ws;
  u32* h16  = (u32*)(ws + OFF_H16);
  u32* s16  = (u32*)(ws + OFF_S16);
  u32* barx = (u32*)(ws + OFF_BARX);
  u16* wspl = (u16*)(ws + OFF_WSPL);
  u16* xhi  = (u16*)(ws + OFF_XHI);
  u16* xlo  = (u16*)(ws + OFF_XLO);
  void* gates = (void*)(ws + OFF_GATES);
  int g32 = (ws_size >= NEED32) ? 1 : 0;

  hipMemsetAsync(barx, 0, 4096, stream);
  // 39,845,888 elements / 4 per thread / 256 threads = 38912 blocks
  k_prep<<<dim3(38912), dim3(256), 0, stream>>>(x, wxr, wxz, wxh, whr, whz, whh,
                                                xhi, xlo, wspl);
  k_gates<<<dim3(6144), dim3(256), 0, stream>>>(xhi, xlo, wspl, bxr, bxz, bxh, gates, g32);
  k_scan<<<dim3(256), dim3(256), 0, stream>>>(st, wspl, gates, g32, h16, s16, barx, yout);
}